// Round 1
// baseline (2609.061 us; speedup 1.0000x reference)
//
#include <hip/hip_runtime.h>

// Problem constants
#define BB 512      // batch
#define TT 50       // seq len
#define EE 256      // embed dim
#define HH 256      // hidden
#define RR 1024     // 2*B rows (queries || replies)
#define KK 512      // E + H
#define NN 1024     // 4*H
#define FORGET_BIAS 2.0f

#define TS 64
#define KT 16
#define LDW (TS + 4)

__global__ __launch_bounds__(256)
void init_kernel(float* __restrict__ h, float* __restrict__ c, float* __restrict__ out)
{
    int idx = blockIdx.x * 256 + threadIdx.x;
    if (idx < RR * HH) { h[idx] = 0.f; c[idx] = 0.f; }
    if (idx == 0) out[0] = 0.f;
}

// z[1024 x 1024] = A[1024 x 512] @ W[512 x 1024]
// A[r][k] = (k < 256) ? emb[id(r,t)][k] : h[r][k-256]
__global__ __launch_bounds__(256)
void gemm_z_kernel(const float* __restrict__ emb,
                   const int* __restrict__ idq,
                   const int* __restrict__ idr,
                   const float* __restrict__ hbuf,
                   const float* __restrict__ W,
                   float* __restrict__ z, int t)
{
    __shared__ float As[KT][LDW];
    __shared__ float Bs[KT][LDW];
    const int tid = threadIdx.x;
    const int tx = tid & 15, ty = tid >> 4;
    const int m0 = blockIdx.x * TS;
    const int n0 = blockIdx.y * TS;

    float acc[4][4] = {};

    for (int kk = 0; kk < KK; kk += KT) {
        #pragma unroll
        for (int i = 0; i < 4; ++i) {
            int l = tid + i * 256;
            int row = l >> 4;      // 0..63
            int k   = l & 15;
            int gr = m0 + row;
            int gk = kk + k;
            float v;
            if (gk < EE) {
                int s = gr >> 9, bidx = gr & (BB - 1);
                int id = (s ? idr : idq)[bidx * TT + t];
                v = emb[id * EE + gk];
            } else {
                v = hbuf[gr * HH + (gk - EE)];
            }
            As[k][row] = v;
        }
        #pragma unroll
        for (int i = 0; i < 4; ++i) {
            int l = tid + i * 256;
            int n = l & 63;
            int k = l >> 6;
            Bs[k][n] = W[(kk + k) * NN + n0 + n];
        }
        __syncthreads();
        #pragma unroll
        for (int k = 0; k < KT; ++k) {
            float4 a4 = *(const float4*)&As[k][ty * 4];
            float4 b4 = *(const float4*)&Bs[k][tx * 4];
            float av[4] = {a4.x, a4.y, a4.z, a4.w};
            float bv[4] = {b4.x, b4.y, b4.z, b4.w};
            #pragma unroll
            for (int i = 0; i < 4; ++i)
                #pragma unroll
                for (int j = 0; j < 4; ++j)
                    acc[i][j] = fmaf(av[i], bv[j], acc[i][j]);
        }
        __syncthreads();
    }
    #pragma unroll
    for (int i = 0; i < 4; ++i) {
        float4 v = {acc[i][0], acc[i][1], acc[i][2], acc[i][3]};
        *(float4*)&z[(m0 + ty * 4 + i) * NN + n0 + tx * 4] = v;
    }
}

// per (row, hh): apply LSTM gates, masked by t < len
__global__ __launch_bounds__(256)
void gate_kernel(const float* __restrict__ z, const float* __restrict__ bias,
                 const float* __restrict__ p_i, const float* __restrict__ p_f,
                 const float* __restrict__ p_o,
                 const int* __restrict__ lenq, const int* __restrict__ lenr,
                 float* __restrict__ h, float* __restrict__ c, int t)
{
    int idx = blockIdx.x * 256 + threadIdx.x;   // 0..262143
    int row = idx >> 8;
    int hh  = idx & (HH - 1);
    int s = row >> 9, bidx = row & (BB - 1);
    int len = (s ? lenr : lenq)[bidx];
    if (t >= len) return;  // state frozen past length

    float cv = c[idx];
    const float* zr = z + row * NN;
    float zi = zr[hh];
    float zj = zr[EE + hh];        // note: gate order i, j, f, o
    float zf = zr[512 + hh];
    float zo = zr[768 + hh];

    float iv = 1.f / (1.f + expf(-(zi + bias[hh]       + p_i[hh] * cv)));
    float fv = 1.f / (1.f + expf(-(zf + bias[512 + hh] + FORGET_BIAS + p_f[hh] * cv)));
    float jv = tanhf(zj + bias[256 + hh]);
    float cn = fv * cv + iv * jv;
    float ov = 1.f / (1.f + expf(-(zo + bias[768 + hh] + p_o[hh] * cn)));
    float hn = ov * tanhf(cn);
    h[idx] = hn;
    c[idx] = cn;
}

// C[M x N] = A[M x K] @ B[K x N], dims multiples of 64/16
__global__ __launch_bounds__(256)
void gemm_nn_kernel(const float* __restrict__ A, const float* __restrict__ B,
                    float* __restrict__ C, int K, int lda, int ldb, int ldc)
{
    __shared__ float As[KT][LDW];
    __shared__ float Bs[KT][LDW];
    const int tid = threadIdx.x;
    const int tx = tid & 15, ty = tid >> 4;
    const int m0 = blockIdx.x * TS;
    const int n0 = blockIdx.y * TS;
    float acc[4][4] = {};
    for (int kk = 0; kk < K; kk += KT) {
        #pragma unroll
        for (int i = 0; i < 4; ++i) {
            int l = tid + i * 256;
            As[l & 15][l >> 4] = A[(m0 + (l >> 4)) * lda + kk + (l & 15)];
            Bs[l >> 6][l & 63] = B[(kk + (l >> 6)) * ldb + n0 + (l & 63)];
        }
        __syncthreads();
        #pragma unroll
        for (int k = 0; k < KT; ++k) {
            float4 a4 = *(const float4*)&As[k][ty * 4];
            float4 b4 = *(const float4*)&Bs[k][tx * 4];
            float av[4] = {a4.x, a4.y, a4.z, a4.w};
            float bv[4] = {b4.x, b4.y, b4.z, b4.w};
            #pragma unroll
            for (int i = 0; i < 4; ++i)
                #pragma unroll
                for (int j = 0; j < 4; ++j)
                    acc[i][j] = fmaf(av[i], bv[j], acc[i][j]);
        }
        __syncthreads();
    }
    #pragma unroll
    for (int i = 0; i < 4; ++i) {
        float4 v = {acc[i][0], acc[i][1], acc[i][2], acc[i][3]};
        *(float4*)&C[(m0 + ty * 4 + i) * ldc + n0 + tx * 4] = v;
    }
}

// C[M x N] = A[M x K] @ B[N x K]^T
__global__ __launch_bounds__(256)
void gemm_nt_kernel(const float* __restrict__ A, const float* __restrict__ B,
                    float* __restrict__ C, int K, int lda, int ldb, int ldc)
{
    __shared__ float As[KT][LDW];
    __shared__ float Bs[KT][LDW];
    const int tid = threadIdx.x;
    const int tx = tid & 15, ty = tid >> 4;
    const int m0 = blockIdx.x * TS;
    const int n0 = blockIdx.y * TS;
    float acc[4][4] = {};
    for (int kk = 0; kk < K; kk += KT) {
        #pragma unroll
        for (int i = 0; i < 4; ++i) {
            int l = tid + i * 256;
            As[l & 15][l >> 4] = A[(m0 + (l >> 4)) * lda + kk + (l & 15)];
            Bs[l & 15][l >> 4] = B[(n0 + (l >> 4)) * ldb + kk + (l & 15)];
        }
        __syncthreads();
        #pragma unroll
        for (int k = 0; k < KT; ++k) {
            float4 a4 = *(const float4*)&As[k][ty * 4];
            float4 b4 = *(const float4*)&Bs[k][tx * 4];
            float av[4] = {a4.x, a4.y, a4.z, a4.w};
            float bv[4] = {b4.x, b4.y, b4.z, b4.w};
            #pragma unroll
            for (int i = 0; i < 4; ++i)
                #pragma unroll
                for (int j = 0; j < 4; ++j)
                    acc[i][j] = fmaf(av[i], bv[j], acc[i][j]);
        }
        __syncthreads();
    }
    #pragma unroll
    for (int i = 0; i < 4; ++i) {
        float4 v = {acc[i][0], acc[i][1], acc[i][2], acc[i][3]};
        *(float4*)&C[(m0 + ty * 4 + i) * ldc + n0 + tx * 4] = v;
    }
}

// loss = sum_{i,j} max(0, D[i,j] - D[j,j] + max(0, wd[i,j]/wd[j,j] - 1))
__global__ __launch_bounds__(256)
void loss_kernel(const float* __restrict__ D, const float* __restrict__ wd,
                 float* __restrict__ out)
{
    int idx = blockIdx.x * 256 + threadIdx.x;  // 0..262143
    int j = idx & (BB - 1);
    float d   = D[idx];
    float pos = D[j * BB + j];
    float w   = wd[idx];
    float wp  = wd[j * BB + j];
    float wn  = fmaxf(0.f, w / wp - 1.f);
    float v   = fmaxf(0.f, d - pos + wn);

    #pragma unroll
    for (int o = 32; o > 0; o >>= 1) v += __shfl_down(v, o);
    __shared__ float sm[4];
    if ((threadIdx.x & 63) == 0) sm[threadIdx.x >> 6] = v;
    __syncthreads();
    if (threadIdx.x == 0) atomicAdd(out, sm[0] + sm[1] + sm[2] + sm[3]);
}

extern "C" void kernel_launch(void* const* d_in, const int* in_sizes, int n_in,
                              void* d_out, int out_size, void* d_ws, size_t ws_size,
                              hipStream_t stream) {
    const int*   idq  = (const int*)d_in[0];
    const int*   idr  = (const int*)d_in[1];
    const int*   lenq = (const int*)d_in[2];
    const int*   lenr = (const int*)d_in[3];
    const float* wd   = (const float*)d_in[4];
    const float* emb  = (const float*)d_in[5];
    const float* W    = (const float*)d_in[6];
    const float* bias = (const float*)d_in[7];
    const float* p_i  = (const float*)d_in[8];
    const float* p_f  = (const float*)d_in[9];
    const float* p_o  = (const float*)d_in[10];
    const float* Mm   = (const float*)d_in[11];
    float* out = (float*)d_out;

    float* ws = (float*)d_ws;
    float* z  = ws;                       // 1024*1024
    float* h  = z  + (size_t)RR * NN;     // 1024*256
    float* c  = h  + (size_t)RR * HH;     // 1024*256
    float* qM = c  + (size_t)RR * HH;     // 512*256
    float* D  = qM + (size_t)BB * HH;     // 512*512

    init_kernel<<<1024, 256, 0, stream>>>(h, c, out);

    // lengths are in [1, 49] => step t=49 never updates; run t = 0..48
    for (int t = 0; t < TT - 1; ++t) {
        gemm_z_kernel<<<dim3(RR / TS, NN / TS), 256, 0, stream>>>(emb, idq, idr, h, W, z, t);
        gate_kernel<<<RR * HH / 256, 256, 0, stream>>>(z, bias, p_i, p_f, p_o,
                                                       lenq, lenr, h, c, t);
    }

    // qM[512x256] = q(h rows 0..511) @ M
    gemm_nn_kernel<<<dim3(BB / TS, HH / TS), 256, 0, stream>>>(h, Mm, qM, HH, HH, HH, HH);
    // D[512x512] = qM @ r^T   (r = h rows 512..1023)
    gemm_nt_kernel<<<dim3(BB / TS, BB / TS), 256, 0, stream>>>(qM, h + (size_t)BB * HH, D,
                                                               HH, HH, HH, BB);
    loss_kernel<<<BB * BB / 256, 256, 0, stream>>>(D, wd, out);
}

// Round 2
// 1883.099 us; speedup vs baseline: 1.3855x; 1.3855x over previous
//
#include <hip/hip_runtime.h>
#include <hip/hip_cooperative_groups.h>

namespace cg = cooperative_groups;

// Problem constants
#define BB 512      // batch
#define TT 50       // seq len
#define EE 256      // embed dim
#define HH 256      // hidden
#define RR 1024     // 2*B rows (queries || replies)
#define NN 1024     // 4*H
#define NSTEP 49    // lengths in [1,49] -> t=49 never updates

using short8 = __attribute__((ext_vector_type(8))) short;
using f32x4  = __attribute__((ext_vector_type(4))) float;

__device__ __forceinline__ short f2bf(float f) {
    unsigned u = __builtin_bit_cast(unsigned, f);
    u += 0x7FFFu + ((u >> 16) & 1u);          // RNE
    return (short)(u >> 16);
}
__device__ __forceinline__ float bf2f(unsigned short s) {
    unsigned u = ((unsigned)s) << 16;
    return __builtin_bit_cast(float, u);
}
__device__ __forceinline__ float sigm(float x) {
    return 1.f / (1.f + __expf(-x));
}
__device__ __forceinline__ float ftanh(float x) {
    return 1.f - 2.f / (__expf(2.f * x) + 1.f);
}

__global__ __launch_bounds__(256)
void init_kernel(int* __restrict__ hb0, float* __restrict__ out)
{
    int idx = blockIdx.x * 256 + threadIdx.x;
    if (idx < RR * HH / 2) hb0[idx] = 0;       // zero h buffer 0 (bf16 pairs)
    if (idx == 0) out[0] = 0.f;
}

// Persistent cooperative LSTM: 256 blocks = 16 row-tiles x 16 hh-tiles.
// Block (rt,ht): rows r0..r0+63, hidden cols hh0..hh0+15, z-cols {g*256+hh0+hc}.
// W slice [512 K][64 cols] staged bf16 to LDS once (XOR-swizzled).
// h double-buffered bf16 in ws; c resident in LDS.
__global__ __launch_bounds__(256)
void lstm_coop_kernel(const float* __restrict__ emb,
                      const int* __restrict__ idq, const int* __restrict__ idr,
                      const int* __restrict__ lenq, const int* __restrict__ lenr,
                      const float* __restrict__ W, const float* __restrict__ bias,
                      const float* __restrict__ p_i, const float* __restrict__ p_f,
                      const float* __restrict__ p_o,
                      short* __restrict__ hb)    // [2][1024][256] bf16
{
    __shared__ char  Ws[64 * 512 * 2];          // [c][k] bf16, swizzled
    __shared__ float c_s[64][17];

    const int tid  = threadIdx.x;
    const int lane = tid & 63;
    const int w    = tid >> 6;
    const int bid  = blockIdx.x;
    const int r0   = (bid >> 4) * 64;
    const int hh0  = (bid & 15) * 16;
    const int hc   = lane & 15;

    // ---- stage W slice -> LDS (once) ----
    for (int q = tid; q < 4096; q += 256) {     // 64 cols x 64 k-chunks of 8
        int c  = q >> 6;
        int k0 = (q & 63) * 8;
        int gcol = (c >> 4) * 256 + hh0 + (c & 15);
        short8 v;
        #pragma unroll
        for (int j = 0; j < 8; ++j)
            v[j] = f2bf(W[(size_t)(k0 + j) * NN + gcol]);
        *(short8*)(Ws + (((c * 1024) + k0 * 2) ^ ((c & 7) << 4))) = v;
    }
    for (int i = tid; i < 64 * 17; i += 256) ((float*)c_s)[i] = 0.f;

    // ---- per-lane constants ----
    const float b_i = bias[hh0 + hc];
    const float b_j = bias[256 + hh0 + hc];
    const float b_f = bias[512 + hh0 + hc];
    const float b_o = bias[768 + hh0 + hc];
    const float pi  = p_i[hh0 + hc];
    const float pf  = p_f[hh0 + hc];
    const float po  = p_o[hh0 + hc];

    int len_r[4];
    #pragma unroll
    for (int reg = 0; reg < 4; ++reg) {
        int gr = r0 + w * 16 + (lane >> 4) * 4 + reg;
        len_r[reg] = (gr < BB) ? lenq[gr] : lenr[gr - BB];
    }

    const int mA  = w * 16 + (lane & 15);       // A-fragment row (local)
    const int grA = r0 + mA;
    const int kpart = (lane >> 4) * 8;

    int baseB[4], swzB[4];
    #pragma unroll
    for (int gi = 0; gi < 4; ++gi) {
        int c = gi * 16 + (lane & 15);
        baseB[gi] = c * 1024;
        swzB[gi]  = (c & 7) << 4;
    }

    __syncthreads();
    cg::grid_group grid = cg::this_grid();

    for (int t = 0; t < NSTEP; ++t) {
        const int p = t & 1;
        const short* hrd = hb + p * (RR * HH);
        short*       hwr = hb + (p ^ 1) * (RR * HH);

        f32x4 acc[4];
        #pragma unroll
        for (int gi = 0; gi < 4; ++gi) acc[gi] = (f32x4){0.f, 0.f, 0.f, 0.f};

        // ---- emb half: k = 0..255 ----
        int id = (grA < BB) ? idq[grA * TT + t] : idr[(grA - BB) * TT + t];
        const float* erow = emb + (size_t)id * EE;
        #pragma unroll
        for (int ks = 0; ks < 8; ++ks) {
            int k0 = ks * 32 + kpart;
            float4 e0 = *(const float4*)(erow + k0);
            float4 e1 = *(const float4*)(erow + k0 + 4);
            short8 a;
            a[0] = f2bf(e0.x); a[1] = f2bf(e0.y); a[2] = f2bf(e0.z); a[3] = f2bf(e0.w);
            a[4] = f2bf(e1.x); a[5] = f2bf(e1.y); a[6] = f2bf(e1.z); a[7] = f2bf(e1.w);
            #pragma unroll
            for (int gi = 0; gi < 4; ++gi) {
                short8 b = *(const short8*)(Ws + ((baseB[gi] + k0 * 2) ^ swzB[gi]));
                acc[gi] = __builtin_amdgcn_mfma_f32_16x16x32_bf16(a, b, acc[gi], 0, 0, 0);
            }
        }
        // ---- h half: k = 256..511 ----
        const short* hrow = hrd + grA * HH;
        #pragma unroll
        for (int ks = 8; ks < 16; ++ks) {
            int kh = (ks - 8) * 32 + kpart;
            short8 a = *(const short8*)(hrow + kh);
            int k0 = ks * 32 + kpart;
            #pragma unroll
            for (int gi = 0; gi < 4; ++gi) {
                short8 b = *(const short8*)(Ws + ((baseB[gi] + k0 * 2) ^ swzB[gi]));
                acc[gi] = __builtin_amdgcn_mfma_f32_16x16x32_bf16(a, b, acc[gi], 0, 0, 0);
            }
        }

        // ---- gates (lane-local: all 4 gates of (r,hc) in this lane) ----
        #pragma unroll
        for (int reg = 0; reg < 4; ++reg) {
            int rl = w * 16 + (lane >> 4) * 4 + reg;
            int gr = r0 + rl;
            float zi = acc[0][reg], zj = acc[1][reg], zf = acc[2][reg], zo = acc[3][reg];
            float cv = c_s[rl][hc];
            float iv = sigm(zi + b_i + pi * cv);
            float fv = sigm(zf + b_f + 2.0f + pf * cv);
            float jv = ftanh(zj + b_j);
            float cn = fv * cv + iv * jv;
            float ov = sigm(zo + b_o + po * cn);
            float hn = ov * ftanh(cn);
            bool upd = (t < len_r[reg]);
            short hold = hrd[gr * HH + hh0 + hc];
            hwr[gr * HH + hh0 + hc] = upd ? f2bf(hn) : hold;
            if (upd) c_s[rl][hc] = cn;
        }
        grid.sync();
    }
}

#define TS 64
#define KT 16
#define LDW (TS + 4)

// qM[512x256] = bf16 h(rows 0..511) @ fp32 M[256x256]
__global__ __launch_bounds__(256)
void gemm_qM_kernel(const short* __restrict__ hA, const float* __restrict__ B,
                    float* __restrict__ C)
{
    __shared__ float As[KT][LDW];
    __shared__ float Bs[KT][LDW];
    const int tid = threadIdx.x;
    const int tx = tid & 15, ty = tid >> 4;
    const int m0 = blockIdx.x * TS;
    const int n0 = blockIdx.y * TS;
    float acc[4][4] = {};
    for (int kk = 0; kk < HH; kk += KT) {
        #pragma unroll
        for (int i = 0; i < 4; ++i) {
            int l = tid + i * 256;
            As[l & 15][l >> 4] = bf2f((unsigned short)hA[(m0 + (l >> 4)) * HH + kk + (l & 15)]);
            Bs[l >> 6][l & 63] = B[(kk + (l >> 6)) * HH + n0 + (l & 63)];
        }
        __syncthreads();
        #pragma unroll
        for (int k = 0; k < KT; ++k) {
            float4 a4 = *(const float4*)&As[k][ty * 4];
            float4 b4 = *(const float4*)&Bs[k][tx * 4];
            float av[4] = {a4.x, a4.y, a4.z, a4.w};
            float bv[4] = {b4.x, b4.y, b4.z, b4.w};
            #pragma unroll
            for (int i = 0; i < 4; ++i)
                #pragma unroll
                for (int j = 0; j < 4; ++j)
                    acc[i][j] = fmaf(av[i], bv[j], acc[i][j]);
        }
        __syncthreads();
    }
    #pragma unroll
    for (int i = 0; i < 4; ++i) {
        float4 v = {acc[i][0], acc[i][1], acc[i][2], acc[i][3]};
        *(float4*)&C[(m0 + ty * 4 + i) * HH + n0 + tx * 4] = v;
    }
}

// D[512x512] = fp32 qM[512x256] @ (bf16 r[512x256])^T
__global__ __launch_bounds__(256)
void gemm_D_kernel(const float* __restrict__ A, const short* __restrict__ hB,
                   float* __restrict__ C)
{
    __shared__ float As[KT][LDW];
    __shared__ float Bs[KT][LDW];
    const int tid = threadIdx.x;
    const int tx = tid & 15, ty = tid >> 4;
    const int m0 = blockIdx.x * TS;
    const int n0 = blockIdx.y * TS;
    float acc[4][4] = {};
    for (int kk = 0; kk < HH; kk += KT) {
        #pragma unroll
        for (int i = 0; i < 4; ++i) {
            int l = tid + i * 256;
            As[l & 15][l >> 4] = A[(m0 + (l >> 4)) * HH + kk + (l & 15)];
            Bs[l & 15][l >> 4] = bf2f((unsigned short)hB[(n0 + (l >> 4)) * HH + kk + (l & 15)]);
        }
        __syncthreads();
        #pragma unroll
        for (int k = 0; k < KT; ++k) {
            float4 a4 = *(const float4*)&As[k][ty * 4];
            float4 b4 = *(const float4*)&Bs[k][tx * 4];
            float av[4] = {a4.x, a4.y, a4.z, a4.w};
            float bv[4] = {b4.x, b4.y, b4.z, b4.w};
            #pragma unroll
            for (int i = 0; i < 4; ++i)
                #pragma unroll
                for (int j = 0; j < 4; ++j)
                    acc[i][j] = fmaf(av[i], bv[j], acc[i][j]);
        }
        __syncthreads();
    }
    #pragma unroll
    for (int i = 0; i < 4; ++i) {
        float4 v = {acc[i][0], acc[i][1], acc[i][2], acc[i][3]};
        *(float4*)&C[(m0 + ty * 4 + i) * BB + n0 + tx * 4] = v;
    }
}

// loss = sum_{i,j} max(0, D[i,j] - D[j,j] + max(0, wd[i,j]/wd[j,j] - 1))
__global__ __launch_bounds__(256)
void loss_kernel(const float* __restrict__ D, const float* __restrict__ wd,
                 float* __restrict__ out)
{
    int idx = blockIdx.x * 256 + threadIdx.x;
    int j = idx & (BB - 1);
    float d   = D[idx];
    float pos = D[j * BB + j];
    float w   = wd[idx];
    float wp  = wd[j * BB + j];
    float wn  = fmaxf(0.f, w / wp - 1.f);
    float v   = fmaxf(0.f, d - pos + wn);

    #pragma unroll
    for (int o = 32; o > 0; o >>= 1) v += __shfl_down(v, o);
    __shared__ float sm[4];
    if ((threadIdx.x & 63) == 0) sm[threadIdx.x >> 6] = v;
    __syncthreads();
    if (threadIdx.x == 0) atomicAdd(out, sm[0] + sm[1] + sm[2] + sm[3]);
}

extern "C" void kernel_launch(void* const* d_in, const int* in_sizes, int n_in,
                              void* d_out, int out_size, void* d_ws, size_t ws_size,
                              hipStream_t stream) {
    const int*   idq  = (const int*)d_in[0];
    const int*   idr  = (const int*)d_in[1];
    const int*   lenq = (const int*)d_in[2];
    const int*   lenr = (const int*)d_in[3];
    const float* wd   = (const float*)d_in[4];
    const float* emb  = (const float*)d_in[5];
    const float* W    = (const float*)d_in[6];
    const float* bias = (const float*)d_in[7];
    const float* p_i  = (const float*)d_in[8];
    const float* p_f  = (const float*)d_in[9];
    const float* p_o  = (const float*)d_in[10];
    const float* Mm   = (const float*)d_in[11];
    float* out = (float*)d_out;

    char* ws = (char*)d_ws;
    short* hb = (short*)ws;                              // 2 x 1024 x 256 bf16 = 1 MB
    float* qM = (float*)(ws + 2 * RR * HH * sizeof(short));   // 512x256 fp32
    float* D  = qM + (size_t)BB * HH;                    // 512x512 fp32

    init_kernel<<<512, 256, 0, stream>>>((int*)hb, out);

    void* args[] = {(void*)&emb, (void*)&idq, (void*)&idr, (void*)&lenq, (void*)&lenr,
                    (void*)&W, (void*)&bias, (void*)&p_i, (void*)&p_f, (void*)&p_o,
                    (void*)&hb};
    hipLaunchCooperativeKernel((void*)lstm_coop_kernel, dim3(256), dim3(256),
                               args, 0, stream);

    // final h is in buffer 1 (t=48 wrote p^1 with p=0)
    short* hfin = hb + (RR * HH);
    gemm_qM_kernel<<<dim3(BB / TS, HH / TS), 256, 0, stream>>>(hfin, Mm, qM);
    gemm_D_kernel<<<dim3(BB / TS, BB / TS), 256, 0, stream>>>(qM, hfin + (size_t)BB * HH, D);
    loss_kernel<<<BB * BB / 256, 256, 0, stream>>>(D, wd, out);
}

// Round 3
// 763.524 us; speedup vs baseline: 3.4171x; 2.4663x over previous
//
#include <hip/hip_runtime.h>

#define TTs 50
#define NSTEP 49

using short8   = __attribute__((ext_vector_type(8))) short;
using ushort4v = __attribute__((ext_vector_type(4))) unsigned short;
using f32x4    = __attribute__((ext_vector_type(4))) float;

__device__ __forceinline__ unsigned short f2bf(float f) {
    unsigned u = __builtin_bit_cast(unsigned, f);
    u += 0x7FFFu + ((u >> 16) & 1u);          // RNE
    return (unsigned short)(u >> 16);
}
__device__ __forceinline__ float bf2f(unsigned short s) {
    unsigned u = ((unsigned)s) << 16;
    return __builtin_bit_cast(float, u);
}
__device__ __forceinline__ float sigm(float x)  { return 1.f / (1.f + __expf(-x)); }
__device__ __forceinline__ float ftanh(float x) { return 1.f - 2.f / (__expf(2.f * x) + 1.f); }

__global__ __launch_bounds__(64)
void init_kernel(float* __restrict__ out) { if (threadIdx.x == 0) out[0] = 0.f; }

// Pack W[koff+k][c] (f32, 512x1024) -> Wp[c][k] (bf16, col-major frag layout).
// grid (64, 2): y=0 -> Wx (k rows 0..255), y=1 -> Wh (rows 256..511)
__global__ __launch_bounds__(256)
void pack_w_kernel(const float* __restrict__ W,
                   unsigned short* __restrict__ Wxp, unsigned short* __restrict__ Whp)
{
    __shared__ float ld[64][65];
    const int koff = blockIdx.y * 256;
    unsigned short* dst = blockIdx.y ? Whp : Wxp;
    const int k0 = (blockIdx.x & 3) * 64, c0 = (blockIdx.x >> 2) * 64;
    const int tid = threadIdx.x;
    #pragma unroll
    for (int i = 0; i < 16; ++i) {
        int idx = tid + i * 256;
        ld[idx >> 6][idx & 63] = W[(size_t)(koff + k0 + (idx >> 6)) * 1024 + c0 + (idx & 63)];
    }
    __syncthreads();
    #pragma unroll
    for (int j = 0; j < 2; ++j) {
        int idx = tid + j * 256;
        int cl = idx >> 3, kc = (idx & 7) * 8;
        short8 v;
        #pragma unroll
        for (int e = 0; e < 8; ++e) v[e] = (short)f2bf(ld[kc + e][cl]);
        *(short8*)(dst + (size_t)(c0 + cl) * 256 + k0 + kc) = v;
    }
}

// X projection: for all (t, row): x = emb[id(row,t)] @ Wx  -> X in consumer frag layout.
// grid (784, 4): x = m-tile (64 rows of one t), y = 256-col slice. 4 waves.
__global__ __launch_bounds__(256, 2)
void xproj_kernel(const float* __restrict__ emb,
                  const int* __restrict__ idq, const int* __restrict__ idr,
                  const unsigned short* __restrict__ Wxp,
                  unsigned short* __restrict__ X)
{
    const int tid = threadIdx.x;
    const int L = tid & 63, w = tid >> 6;
    const int mb = blockIdx.x * 64;
    const int t = mb >> 10, r0 = mb & 1023;
    const int cb = blockIdx.y * 256;

    const int gr = r0 + w * 16 + (L & 15);
    const int id = (gr < 512) ? idq[gr * TTs + t] : idr[(gr - 512) * TTs + t];
    const float* erow = emb + (size_t)id * 256 + (L >> 4) * 8;

    const unsigned short* bp[16];
    #pragma unroll
    for (int f = 0; f < 16; ++f) {
        int c = cb + f * 16 + (L & 15);
        bp[f] = Wxp + (size_t)c * 256 + (L >> 4) * 8;
    }
    f32x4 acc[16];
    #pragma unroll
    for (int f = 0; f < 16; ++f) acc[f] = (f32x4){0.f, 0.f, 0.f, 0.f};

    #pragma unroll
    for (int ks = 0; ks < 8; ++ks) {
        float4 e0 = *(const float4*)(erow + ks * 32);
        float4 e1 = *(const float4*)(erow + ks * 32 + 4);
        short8 a;
        a[0] = (short)f2bf(e0.x); a[1] = (short)f2bf(e0.y);
        a[2] = (short)f2bf(e0.z); a[3] = (short)f2bf(e0.w);
        a[4] = (short)f2bf(e1.x); a[5] = (short)f2bf(e1.y);
        a[6] = (short)f2bf(e1.z); a[7] = (short)f2bf(e1.w);
        #pragma unroll
        for (int f = 0; f < 16; ++f) {
            short8 b = *(const short8*)(bp[f] + ks * 32);
            acc[f] = __builtin_amdgcn_mfma_f32_16x16x32_bf16(a, b, acc[f], 0, 0, 0);
        }
    }
    const int rblk = r0 >> 4;
    #pragma unroll
    for (int f = 0; f < 16; ++f) {
        int c00 = cb + f * 16;
        int slot = ((c00 >> 6) & 3) * 16 + (c00 >> 8) * 4 + ((c00 >> 4) & 3);
        size_t off = (((size_t)(t * 64 + rblk + w)) * 64 + slot) * 256 + L * 4;
        ushort4v v;
        v[0] = f2bf(acc[f][0]); v[1] = f2bf(acc[f][1]);
        v[2] = f2bf(acc[f][2]); v[3] = f2bf(acc[f][3]);
        *(ushort4v*)(X + off) = v;
    }
}

// Recurrent loop: 64 blocks x 16 rows, 8 waves, block-local (no grid sync).
// Wave w covers z-cols {g*256 + basew + fi*16 + lanelo | g=0..3, fi=0..1}.
__global__ __launch_bounds__(512, 2)
void lstm_loop_kernel(const unsigned short* __restrict__ X,
                      const unsigned short* __restrict__ Whp,
                      const float* __restrict__ bias,
                      const float* __restrict__ p_i, const float* __restrict__ p_f,
                      const float* __restrict__ p_o,
                      const int* __restrict__ lenq, const int* __restrict__ lenr,
                      unsigned short* __restrict__ hfin)
{
    __shared__ unsigned short hl[2 * 16 * 256];    // double-buffered h, XOR-swizzled
    const int tid = threadIdx.x;
    const int L = tid & 63, w = tid >> 6;          // w 0..7
    const int blk = blockIdx.x;                    // 0..63 (16-row groups)
    const int r0g = blk * 16;
    const int lanelo = L & 15, lhi = L >> 4;
    const int basew = (w & 3) * 64 + (w >> 2) * 32;

    for (int i = tid; i < 2 * 16 * 256; i += 512) hl[i] = 0;

    const unsigned short* bp[8];
    #pragma unroll
    for (int f = 0; f < 8; ++f) {
        int c = (f >> 1) * 256 + basew + (f & 1) * 16 + lanelo;
        bp[f] = Whp + (size_t)c * 256 + lhi * 8;
    }
    int xoff[8];
    #pragma unroll
    for (int f = 0; f < 8; ++f) {
        int slot = (w & 3) * 16 + (f >> 1) * 4 + (w >> 2) * 2 + (f & 1);
        xoff[f] = slot * 256 + L * 4;
    }
    const unsigned short* xb = X + (size_t)blk * 16384;

    int ards[8];
    #pragma unroll
    for (int ks = 0; ks < 8; ++ks) {
        int base = lanelo * 512 + ks * 64 + lhi * 16;
        ards[ks] = base ^ ((lanelo & 7) << 4);
    }
    int awr[2][4];
    #pragma unroll
    for (int fi = 0; fi < 2; ++fi)
        #pragma unroll
        for (int reg = 0; reg < 4; ++reg) {
            int r = lhi * 4 + reg;
            int hh = basew + fi * 16 + lanelo;
            awr[fi][reg] = (r * 512 + hh * 2) ^ ((r & 7) << 4);
        }

    float bi[2], bj[2], bff[2], bo[2], pii[2], pff[2], poo[2];
    #pragma unroll
    for (int fi = 0; fi < 2; ++fi) {
        int hh = basew + fi * 16 + lanelo;
        bi[fi]  = bias[hh];       bj[fi] = bias[256 + hh];
        bff[fi] = bias[512 + hh] + 2.0f;   // + FORGET_BIAS
        bo[fi]  = bias[768 + hh];
        pii[fi] = p_i[hh]; pff[fi] = p_f[hh]; poo[fi] = p_o[hh];
    }
    int len_[4];
    #pragma unroll
    for (int reg = 0; reg < 4; ++reg) {
        int gr = r0g + lhi * 4 + reg;
        len_[reg] = (gr < 512) ? lenq[gr] : lenr[gr - 512];
    }

    float cst[2][4] = {};
    unsigned short hreg[2][4] = {};
    char* hlb = (char*)hl;

    __syncthreads();

    for (int t = 0; t < NSTEP; ++t) {
        const int prd = (t & 1) * 8192;
        const int pwr = 8192 - prd;
        const unsigned short* xt = xb + (size_t)t * 1048576;

        // x loads issue here, consumed only at gate time (hidden under MFMA)
        ushort4v xr[8];
        #pragma unroll
        for (int f = 0; f < 8; ++f) xr[f] = *(const ushort4v*)(xt + xoff[f]);

        f32x4 acc[8];
        #pragma unroll
        for (int f = 0; f < 8; ++f) acc[f] = (f32x4){0.f, 0.f, 0.f, 0.f};

        #pragma unroll
        for (int ks = 0; ks < 8; ++ks) {
            short8 a = *(const short8*)(hlb + prd + ards[ks]);
            #pragma unroll
            for (int f = 0; f < 8; ++f) {
                short8 b = *(const short8*)(bp[f] + ks * 32);
                acc[f] = __builtin_amdgcn_mfma_f32_16x16x32_bf16(a, b, acc[f], 0, 0, 0);
            }
        }

        #pragma unroll
        for (int fi = 0; fi < 2; ++fi)
            #pragma unroll
            for (int reg = 0; reg < 4; ++reg) {
                float cv = cst[fi][reg];
                float zi = acc[0 + fi][reg] + bf2f(xr[0 + fi][reg]);
                float zj = acc[2 + fi][reg] + bf2f(xr[2 + fi][reg]);
                float zf = acc[4 + fi][reg] + bf2f(xr[4 + fi][reg]);
                float zo = acc[6 + fi][reg] + bf2f(xr[6 + fi][reg]);
                float iv = sigm(zi + bi[fi] + pii[fi] * cv);
                float fv = sigm(zf + bff[fi] + pff[fi] * cv);
                float jv = ftanh(zj + bj[fi]);
                float cn = fv * cv + iv * jv;
                float ov = sigm(zo + bo[fi] + poo[fi] * cn);
                float hn = ov * ftanh(cn);
                bool upd = (t < len_[reg]);
                unsigned short hv = upd ? f2bf(hn) : hreg[fi][reg];
                if (upd) cst[fi][reg] = cn;
                hreg[fi][reg] = hv;
                *(unsigned short*)(hlb + pwr + awr[fi][reg]) = hv;
            }
        __syncthreads();
    }

    #pragma unroll
    for (int fi = 0; fi < 2; ++fi)
        #pragma unroll
        for (int reg = 0; reg < 4; ++reg) {
            int gr = r0g + lhi * 4 + reg;
            int hh = basew + fi * 16 + lanelo;
            hfin[(size_t)gr * 256 + hh] = hreg[fi][reg];
        }
}

#define TS 64
#define KT 16
#define LDW (TS + 4)

// qM[512x256] = bf16 h(rows 0..511) @ fp32 M[256x256]
__global__ __launch_bounds__(256)
void gemm_qM_kernel(const unsigned short* __restrict__ hA, const float* __restrict__ B,
                    float* __restrict__ C)
{
    __shared__ float As[KT][LDW];
    __shared__ float Bs[KT][LDW];
    const int tid = threadIdx.x;
    const int tx = tid & 15, ty = tid >> 4;
    const int m0 = blockIdx.x * TS, n0 = blockIdx.y * TS;
    float acc[4][4] = {};
    for (int kk = 0; kk < 256; kk += KT) {
        #pragma unroll
        for (int i = 0; i < 4; ++i) {
            int l = tid + i * 256;
            As[l & 15][l >> 4] = bf2f(hA[(m0 + (l >> 4)) * 256 + kk + (l & 15)]);
            Bs[l >> 6][l & 63] = B[(kk + (l >> 6)) * 256 + n0 + (l & 63)];
        }
        __syncthreads();
        #pragma unroll
        for (int k = 0; k < KT; ++k) {
            float4 a4 = *(const float4*)&As[k][ty * 4];
            float4 b4 = *(const float4*)&Bs[k][tx * 4];
            float av[4] = {a4.x, a4.y, a4.z, a4.w};
            float bv[4] = {b4.x, b4.y, b4.z, b4.w};
            #pragma unroll
            for (int i = 0; i < 4; ++i)
                #pragma unroll
                for (int j = 0; j < 4; ++j)
                    acc[i][j] = fmaf(av[i], bv[j], acc[i][j]);
        }
        __syncthreads();
    }
    #pragma unroll
    for (int i = 0; i < 4; ++i) {
        float4 v = {acc[i][0], acc[i][1], acc[i][2], acc[i][3]};
        *(float4*)&C[(m0 + ty * 4 + i) * 256 + n0 + tx * 4] = v;
    }
}

// D[512x512] = fp32 qM[512x256] @ (bf16 r[512x256])^T
__global__ __launch_bounds__(256)
void gemm_D_kernel(const float* __restrict__ A, const unsigned short* __restrict__ hB,
                   float* __restrict__ C)
{
    __shared__ float As[KT][LDW];
    __shared__ float Bs[KT][LDW];
    const int tid = threadIdx.x;
    const int tx = tid & 15, ty = tid >> 4;
    const int m0 = blockIdx.x * TS, n0 = blockIdx.y * TS;
    float acc[4][4] = {};
    for (int kk = 0; kk < 256; kk += KT) {
        #pragma unroll
        for (int i = 0; i < 4; ++i) {
            int l = tid + i * 256;
            As[l & 15][l >> 4] = A[(m0 + (l >> 4)) * 256 + kk + (l & 15)];
            Bs[l & 15][l >> 4] = bf2f(hB[(n0 + (l >> 4)) * 256 + kk + (l & 15)]);
        }
        __syncthreads();
        #pragma unroll
        for (int k = 0; k < KT; ++k) {
            float4 a4 = *(const float4*)&As[k][ty * 4];
            float4 b4 = *(const float4*)&Bs[k][tx * 4];
            float av[4] = {a4.x, a4.y, a4.z, a4.w};
            float bv[4] = {b4.x, b4.y, b4.z, b4.w};
            #pragma unroll
            for (int i = 0; i < 4; ++i)
                #pragma unroll
                for (int j = 0; j < 4; ++j)
                    acc[i][j] = fmaf(av[i], bv[j], acc[i][j]);
        }
        __syncthreads();
    }
    #pragma unroll
    for (int i = 0; i < 4; ++i) {
        float4 v = {acc[i][0], acc[i][1], acc[i][2], acc[i][3]};
        *(float4*)&C[(m0 + ty * 4 + i) * 512 + n0 + tx * 4] = v;
    }
}

__global__ __launch_bounds__(256)
void loss_kernel(const float* __restrict__ D, const float* __restrict__ wd,
                 float* __restrict__ out)
{
    int idx = blockIdx.x * 256 + threadIdx.x;
    int j = idx & 511;
    float d   = D[idx];
    float pos = D[j * 512 + j];
    float ww  = wd[idx];
    float wp  = wd[j * 512 + j];
    float wn  = fmaxf(0.f, ww / wp - 1.f);
    float v   = fmaxf(0.f, d - pos + wn);
    #pragma unroll
    for (int o = 32; o > 0; o >>= 1) v += __shfl_down(v, o);
    __shared__ float sm[4];
    if ((threadIdx.x & 63) == 0) sm[threadIdx.x >> 6] = v;
    __syncthreads();
    if (threadIdx.x == 0) atomicAdd(out, sm[0] + sm[1] + sm[2] + sm[3]);
}

extern "C" void kernel_launch(void* const* d_in, const int* in_sizes, int n_in,
                              void* d_out, int out_size, void* d_ws, size_t ws_size,
                              hipStream_t stream) {
    const int*   idq  = (const int*)d_in[0];
    const int*   idr  = (const int*)d_in[1];
    const int*   lenq = (const int*)d_in[2];
    const int*   lenr = (const int*)d_in[3];
    const float* wd   = (const float*)d_in[4];
    const float* emb  = (const float*)d_in[5];
    const float* W    = (const float*)d_in[6];
    const float* bias = (const float*)d_in[7];
    const float* p_i  = (const float*)d_in[8];
    const float* p_f  = (const float*)d_in[9];
    const float* p_o  = (const float*)d_in[10];
    const float* Mm   = (const float*)d_in[11];
    float* out = (float*)d_out;

    char* ws = (char*)d_ws;
    unsigned short* X    = (unsigned short*)ws;                 // 49*1024*1024 bf16 = 102,760,448 B
    char* p = ws + (size_t)NSTEP * 1048576 * 2;
    unsigned short* hfin = (unsigned short*)p;  p += 1024 * 256 * 2;   // 512 KB
    unsigned short* Wxp  = (unsigned short*)p;  p += 1024 * 256 * 2;   // 512 KB
    unsigned short* Whp  = (unsigned short*)p;  p += 1024 * 256 * 2;   // 512 KB
    float* qM = (float*)p;  p += 512 * 256 * 4;                        // 512 KB
    float* D  = (float*)p;                                             // 1 MB

    init_kernel<<<1, 64, 0, stream>>>(out);
    pack_w_kernel<<<dim3(64, 2), 256, 0, stream>>>(W, Wxp, Whp);
    xproj_kernel<<<dim3(784, 4), 256, 0, stream>>>(emb, idq, idr, Wxp, X);
    lstm_loop_kernel<<<64, 512, 0, stream>>>(X, Whp, bias, p_i, p_f, p_o,
                                             lenq, lenr, hfin);
    gemm_qM_kernel<<<dim3(8, 4), 256, 0, stream>>>(hfin, Mm, qM);
    gemm_D_kernel<<<dim3(8, 8), 256, 0, stream>>>(qM, hfin + 512 * 256, D);
    loss_kernel<<<1024, 256, 0, stream>>>(D, wd, out);
}

// Round 4
// 756.275 us; speedup vs baseline: 3.4499x; 1.0096x over previous
//
#include <hip/hip_runtime.h>

#define TTs 50
#define NSTEP 49

using short8   = __attribute__((ext_vector_type(8))) short;
using ushort4v = __attribute__((ext_vector_type(4))) unsigned short;
using f32x4    = __attribute__((ext_vector_type(4))) float;

__device__ __forceinline__ unsigned short f2bf(float f) {
    unsigned u = __builtin_bit_cast(unsigned, f);
    u += 0x7FFFu + ((u >> 16) & 1u);          // RNE
    return (unsigned short)(u >> 16);
}
__device__ __forceinline__ float bf2f(unsigned short s) {
    unsigned u = ((unsigned)s) << 16;
    return __builtin_bit_cast(float, u);
}
__device__ __forceinline__ float sigm(float x)  { return 1.f / (1.f + __expf(-x)); }
__device__ __forceinline__ float ftanh(float x) { return 1.f - 2.f / (__expf(2.f * x) + 1.f); }

__global__ __launch_bounds__(64)
void init_kernel(float* __restrict__ out) { if (threadIdx.x == 0) out[0] = 0.f; }

// Pack W[koff+k][c] (f32, 512x1024) -> Wp[c][k] (bf16, col-major frag layout).
// grid (64, 2): y=0 -> Wx (k rows 0..255), y=1 -> Wh (rows 256..511)
__global__ __launch_bounds__(256)
void pack_w_kernel(const float* __restrict__ W,
                   unsigned short* __restrict__ Wxp, unsigned short* __restrict__ Whp)
{
    __shared__ float ld[64][65];
    const int koff = blockIdx.y * 256;
    unsigned short* dst = blockIdx.y ? Whp : Wxp;
    const int k0 = (blockIdx.x & 3) * 64, c0 = (blockIdx.x >> 2) * 64;
    const int tid = threadIdx.x;
    #pragma unroll
    for (int i = 0; i < 16; ++i) {
        int idx = tid + i * 256;
        ld[idx >> 6][idx & 63] = W[(size_t)(koff + k0 + (idx >> 6)) * 1024 + c0 + (idx & 63)];
    }
    __syncthreads();
    #pragma unroll
    for (int j = 0; j < 2; ++j) {
        int idx = tid + j * 256;
        int cl = idx >> 3, kc = (idx & 7) * 8;
        short8 v;
        #pragma unroll
        for (int e = 0; e < 8; ++e) v[e] = (short)f2bf(ld[kc + e][cl]);
        *(short8*)(dst + (size_t)(c0 + cl) * 256 + k0 + kc) = v;
    }
}

// X projection: x = emb[id(row,t)] @ Wx for all (t,row) -> X in consumer frag layout.
// X element offset: t*1048576 + rblk*16384 + slot*256 + L*4  (slot = zcol/16)
// grid (784, 8): x = 64-row tile of one t; y = 128-col slice. 4 waves = 4 row-groups.
__global__ __launch_bounds__(256, 2)
void xproj_kernel(const float* __restrict__ emb,
                  const int* __restrict__ idq, const int* __restrict__ idr,
                  const unsigned short* __restrict__ Wxp,
                  unsigned short* __restrict__ X)
{
    const int tid = threadIdx.x;
    const int L = tid & 63, w = tid >> 6;          // w = row-group 0..3
    const int mb = blockIdx.x * 64;
    const int t = mb >> 10, r0 = mb & 1023;
    const int cb = blockIdx.y * 128;

    const int gr = r0 + w * 16 + (L & 15);
    const int id = (gr < 512) ? idq[gr * TTs + t] : idr[(gr - 512) * TTs + t];
    const float* erow = emb + (size_t)id * 256 + (L >> 4) * 8;

    const unsigned short* bp[8];
    #pragma unroll
    for (int f = 0; f < 8; ++f) {
        int c = cb + f * 16 + (L & 15);
        bp[f] = Wxp + (size_t)c * 256 + (L >> 4) * 8;
    }
    f32x4 acc[8];
    #pragma unroll
    for (int f = 0; f < 8; ++f) acc[f] = (f32x4){0.f, 0.f, 0.f, 0.f};

    #pragma unroll
    for (int ks = 0; ks < 8; ++ks) {
        float4 e0 = *(const float4*)(erow + ks * 32);
        float4 e1 = *(const float4*)(erow + ks * 32 + 4);
        short8 a;
        a[0] = (short)f2bf(e0.x); a[1] = (short)f2bf(e0.y);
        a[2] = (short)f2bf(e0.z); a[3] = (short)f2bf(e0.w);
        a[4] = (short)f2bf(e1.x); a[5] = (short)f2bf(e1.y);
        a[6] = (short)f2bf(e1.z); a[7] = (short)f2bf(e1.w);
        #pragma unroll
        for (int f = 0; f < 8; ++f) {
            short8 b = *(const short8*)(bp[f] + ks * 32);
            acc[f] = __builtin_amdgcn_mfma_f32_16x16x32_bf16(a, b, acc[f], 0, 0, 0);
        }
    }
    const int rblk = (r0 >> 4) + w;
    #pragma unroll
    for (int f = 0; f < 8; ++f) {
        int slot = (cb >> 4) + f;
        size_t off = (((size_t)(t * 64 + rblk)) * 64 + slot) * 256 + L * 4;
        ushort4v v;
        v[0] = f2bf(acc[f][0]); v[1] = f2bf(acc[f][1]);
        v[2] = f2bf(acc[f][2]); v[3] = f2bf(acc[f][3]);
        *(ushort4v*)(X + off) = v;
    }
}

// Recurrent loop: 64 blocks x 16 rows, 16 waves (1024 thr).
// Wave w owns z-cols {g*256 + w*16 + lanelo | g=0..3} -> Wh slice lives in
// 128 VGPRs (loaded once). h double-buffered in 16 KB LDS. Gates lane-local.
__global__ __launch_bounds__(1024)
void lstm_loop_kernel(const unsigned short* __restrict__ X,
                      const unsigned short* __restrict__ Whp,
                      const float* __restrict__ bias,
                      const float* __restrict__ p_i, const float* __restrict__ p_f,
                      const float* __restrict__ p_o,
                      const int* __restrict__ lenq, const int* __restrict__ lenr,
                      unsigned short* __restrict__ hfin)
{
    __shared__ unsigned short hl[2 * 16 * 256];    // double-buffered h, XOR-swizzled
    const int tid = threadIdx.x;
    const int L = tid & 63, w = tid >> 6;          // w 0..15
    const int blk = blockIdx.x;                    // 16-row group
    const int r0g = blk * 16;
    const int lanelo = L & 15, lhi = L >> 4;
    const int hh = w * 16 + lanelo;

    for (int i = tid; i < 2 * 16 * 256; i += 1024) hl[i] = 0;

    // ---- Wh slice -> registers (persistent) ----
    short8 Bw[8][4];
    #pragma unroll
    for (int g = 0; g < 4; ++g) {
        const unsigned short* base = Whp + (size_t)(g * 256 + hh) * 256 + lhi * 8;
        #pragma unroll
        for (int ks = 0; ks < 8; ++ks)
            Bw[ks][g] = *(const short8*)(base + ks * 32);
    }

    int xoff[4];
    #pragma unroll
    for (int g = 0; g < 4; ++g) xoff[g] = (g * 16 + w) * 256 + L * 4;
    const unsigned short* xb = X + (size_t)blk * 16384;

    int ards[8];
    #pragma unroll
    for (int ks = 0; ks < 8; ++ks)
        ards[ks] = (lanelo * 512 + ks * 64 + lhi * 16) ^ ((lanelo & 7) << 4);
    int awr[4];
    #pragma unroll
    for (int reg = 0; reg < 4; ++reg) {
        int r = lhi * 4 + reg;
        awr[reg] = (r * 512 + hh * 2) ^ ((r & 7) << 4);
    }

    const float bi  = bias[hh];
    const float bj  = bias[256 + hh];
    const float bf_ = bias[512 + hh] + 2.0f;       // + FORGET_BIAS
    const float bo  = bias[768 + hh];
    const float pii = p_i[hh], pff = p_f[hh], poo = p_o[hh];

    int len_[4];
    #pragma unroll
    for (int reg = 0; reg < 4; ++reg) {
        int gr = r0g + lhi * 4 + reg;
        len_[reg] = (gr < 512) ? lenq[gr] : lenr[gr - 512];
    }

    float cst[4] = {};
    unsigned short hreg[4] = {};
    char* hlb = (char*)hl;

    __syncthreads();

    for (int t = 0; t < NSTEP; ++t) {
        const int prd = (t & 1) * 8192;
        const int pwr = 8192 - prd;
        const unsigned short* xt = xb + (size_t)t * 1048576;

        ushort4v xr[4];                            // consumed at gate time
        #pragma unroll
        for (int g = 0; g < 4; ++g) xr[g] = *(const ushort4v*)(xt + xoff[g]);

        f32x4 acc[4];
        #pragma unroll
        for (int g = 0; g < 4; ++g) acc[g] = (f32x4){0.f, 0.f, 0.f, 0.f};

        #pragma unroll
        for (int ks = 0; ks < 8; ++ks) {
            short8 a = *(const short8*)(hlb + prd + ards[ks]);
            #pragma unroll
            for (int g = 0; g < 4; ++g)
                acc[g] = __builtin_amdgcn_mfma_f32_16x16x32_bf16(a, Bw[ks][g], acc[g], 0, 0, 0);
        }

        #pragma unroll
        for (int reg = 0; reg < 4; ++reg) {
            float cv = cst[reg];
            float zi = acc[0][reg] + bf2f(xr[0][reg]);
            float zj = acc[1][reg] + bf2f(xr[1][reg]);
            float zf = acc[2][reg] + bf2f(xr[2][reg]);
            float zo = acc[3][reg] + bf2f(xr[3][reg]);
            float iv = sigm(zi + bi + pii * cv);
            float fv = sigm(zf + bf_ + pff * cv);
            float jv = ftanh(zj + bj);
            float cn = fv * cv + iv * jv;
            float ov = sigm(zo + bo + poo * cn);
            float hn = ov * ftanh(cn);
            bool upd = (t < len_[reg]);
            unsigned short hv = upd ? f2bf(hn) : hreg[reg];
            if (upd) cst[reg] = cn;
            hreg[reg] = hv;
            *(unsigned short*)(hlb + pwr + awr[reg]) = hv;
        }
        __syncthreads();
    }

    #pragma unroll
    for (int reg = 0; reg < 4; ++reg)
        hfin[(size_t)(r0g + lhi * 4 + reg) * 256 + hh] = hreg[reg];
}

#define TS 64
#define KT 16
#define LDW (TS + 4)

// qM[512x256] = bf16 h(rows 0..511) @ fp32 M[256x256]
__global__ __launch_bounds__(256)
void gemm_qM_kernel(const unsigned short* __restrict__ hA, const float* __restrict__ B,
                    float* __restrict__ C)
{
    __shared__ float As[KT][LDW];
    __shared__ float Bs[KT][LDW];
    const int tid = threadIdx.x;
    const int tx = tid & 15, ty = tid >> 4;
    const int m0 = blockIdx.x * TS, n0 = blockIdx.y * TS;
    float acc[4][4] = {};
    for (int kk = 0; kk < 256; kk += KT) {
        #pragma unroll
        for (int i = 0; i < 4; ++i) {
            int l = tid + i * 256;
            As[l & 15][l >> 4] = bf2f(hA[(m0 + (l >> 4)) * 256 + kk + (l & 15)]);
            Bs[l >> 6][l & 63] = B[(kk + (l >> 6)) * 256 + n0 + (l & 63)];
        }
        __syncthreads();
        #pragma unroll
        for (int k = 0; k < KT; ++k) {
            float4 a4 = *(const float4*)&As[k][ty * 4];
            float4 b4 = *(const float4*)&Bs[k][tx * 4];
            float av[4] = {a4.x, a4.y, a4.z, a4.w};
            float bv[4] = {b4.x, b4.y, b4.z, b4.w};
            #pragma unroll
            for (int i = 0; i < 4; ++i)
                #pragma unroll
                for (int j = 0; j < 4; ++j)
                    acc[i][j] = fmaf(av[i], bv[j], acc[i][j]);
        }
        __syncthreads();
    }
    #pragma unroll
    for (int i = 0; i < 4; ++i) {
        float4 v = {acc[i][0], acc[i][1], acc[i][2], acc[i][3]};
        *(float4*)&C[(m0 + ty * 4 + i) * 256 + n0 + tx * 4] = v;
    }
}

// D[512x512] = fp32 qM[512x256] @ (bf16 r[512x256])^T
__global__ __launch_bounds__(256)
void gemm_D_kernel(const float* __restrict__ A, const unsigned short* __restrict__ hB,
                   float* __restrict__ C)
{
    __shared__ float As[KT][LDW];
    __shared__ float Bs[KT][LDW];
    const int tid = threadIdx.x;
    const int tx = tid & 15, ty = tid >> 4;
    const int m0 = blockIdx.x * TS, n0 = blockIdx.y * TS;
    float acc[4][4] = {};
    for (int kk = 0; kk < 256; kk += KT) {
        #pragma unroll
        for (int i = 0; i < 4; ++i) {
            int l = tid + i * 256;
            As[l & 15][l >> 4] = A[(m0 + (l >> 4)) * 256 + kk + (l & 15)];
            Bs[l & 15][l >> 4] = bf2f(hB[(n0 + (l >> 4)) * 256 + kk + (l & 15)]);
        }
        __syncthreads();
        #pragma unroll
        for (int k = 0; k < KT; ++k) {
            float4 a4 = *(const float4*)&As[k][ty * 4];
            float4 b4 = *(const float4*)&Bs[k][tx * 4];
            float av[4] = {a4.x, a4.y, a4.z, a4.w};
            float bv[4] = {b4.x, b4.y, b4.z, b4.w};
            #pragma unroll
            for (int i = 0; i < 4; ++i)
                #pragma unroll
                for (int j = 0; j < 4; ++j)
                    acc[i][j] = fmaf(av[i], bv[j], acc[i][j]);
        }
        __syncthreads();
    }
    #pragma unroll
    for (int i = 0; i < 4; ++i) {
        float4 v = {acc[i][0], acc[i][1], acc[i][2], acc[i][3]};
        *(float4*)&C[(m0 + ty * 4 + i) * 512 + n0 + tx * 4] = v;
    }
}

__global__ __launch_bounds__(256)
void loss_kernel(const float* __restrict__ D, const float* __restrict__ wd,
                 float* __restrict__ out)
{
    int idx = blockIdx.x * 256 + threadIdx.x;
    int j = idx & 511;
    float d   = D[idx];
    float pos = D[j * 512 + j];
    float ww  = wd[idx];
    float wp  = wd[j * 512 + j];
    float wn  = fmaxf(0.f, ww / wp - 1.f);
    float v   = fmaxf(0.f, d - pos + wn);
    #pragma unroll
    for (int o = 32; o > 0; o >>= 1) v += __shfl_down(v, o);
    __shared__ float sm[4];
    if ((threadIdx.x & 63) == 0) sm[threadIdx.x >> 6] = v;
    __syncthreads();
    if (threadIdx.x == 0) atomicAdd(out, sm[0] + sm[1] + sm[2] + sm[3]);
}

extern "C" void kernel_launch(void* const* d_in, const int* in_sizes, int n_in,
                              void* d_out, int out_size, void* d_ws, size_t ws_size,
                              hipStream_t stream) {
    const int*   idq  = (const int*)d_in[0];
    const int*   idr  = (const int*)d_in[1];
    const int*   lenq = (const int*)d_in[2];
    const int*   lenr = (const int*)d_in[3];
    const float* wd   = (const float*)d_in[4];
    const float* emb  = (const float*)d_in[5];
    const float* W    = (const float*)d_in[6];
    const float* bias = (const float*)d_in[7];
    const float* p_i  = (const float*)d_in[8];
    const float* p_f  = (const float*)d_in[9];
    const float* p_o  = (const float*)d_in[10];
    const float* Mm   = (const float*)d_in[11];
    float* out = (float*)d_out;

    char* ws = (char*)d_ws;
    unsigned short* X    = (unsigned short*)ws;                 // 49*1024*1024 bf16
    char* p = ws + (size_t)NSTEP * 1048576 * 2;
    unsigned short* hfin = (unsigned short*)p;  p += 1024 * 256 * 2;
    unsigned short* Wxp  = (unsigned short*)p;  p += 1024 * 256 * 2;
    unsigned short* Whp  = (unsigned short*)p;  p += 1024 * 256 * 2;
    float* qM = (float*)p;  p += 512 * 256 * 4;
    float* D  = (float*)p;

    init_kernel<<<1, 64, 0, stream>>>(out);
    pack_w_kernel<<<dim3(64, 2), 256, 0, stream>>>(W, Wxp, Whp);
    xproj_kernel<<<dim3(784, 8), 256, 0, stream>>>(emb, idq, idr, Wxp, X);
    lstm_loop_kernel<<<64, 1024, 0, stream>>>(X, Whp, bias, p_i, p_f, p_o,
                                              lenq, lenr, hfin);
    gemm_qM_kernel<<<dim3(8, 4), 256, 0, stream>>>(hfin, Mm, qM);
    gemm_D_kernel<<<dim3(8, 8), 256, 0, stream>>>(qM, hfin + 512 * 256, D);
    loss_kernel<<<1024, 256, 0, stream>>>(D, wd, out);
}

// Round 5
// 488.360 us; speedup vs baseline: 5.3425x; 1.5486x over previous
//
#include <hip/hip_runtime.h>

#define TTs 50
#define NSTEP 49

using short8   = __attribute__((ext_vector_type(8))) short;
using ushort4v = __attribute__((ext_vector_type(4))) unsigned short;
using f32x4    = __attribute__((ext_vector_type(4))) float;
using int4v    = __attribute__((ext_vector_type(4))) int;

__device__ __forceinline__ unsigned short f2bf(float f) {
    unsigned u = __builtin_bit_cast(unsigned, f);
    u += 0x7FFFu + ((u >> 16) & 1u);          // RNE
    return (unsigned short)(u >> 16);
}
__device__ __forceinline__ float bf2f(unsigned short s) {
    unsigned u = ((unsigned)s) << 16;
    return __builtin_bit_cast(float, u);
}
__device__ __forceinline__ float sigm(float x)  { return 1.f / (1.f + __expf(-x)); }
__device__ __forceinline__ float ftanh(float x) { return 1.f - 2.f / (__expf(2.f * x) + 1.f); }

#define WH_SCALE 512.f
#define H_SCALE  127.f

__global__ __launch_bounds__(64)
void init_kernel(float* __restrict__ out) { if (threadIdx.x == 0) out[0] = 0.f; }

// Pack W (f32 [512][1024]):
//  y=0: Wx rows 0..255   -> Wxp bf16 [c][k] col-major frag layout
//  y=1: Wh rows 256..511 -> Wq  int8 [c][k] col-major, scaled by 512
__global__ __launch_bounds__(256)
void pack_w_kernel(const float* __restrict__ W,
                   unsigned short* __restrict__ Wxp, signed char* __restrict__ Wq)
{
    __shared__ float ld[64][65];
    const int koff = blockIdx.y * 256;
    const int k0 = (blockIdx.x & 3) * 64, c0 = (blockIdx.x >> 2) * 64;
    const int tid = threadIdx.x;
    #pragma unroll
    for (int i = 0; i < 16; ++i) {
        int idx = tid + i * 256;
        ld[idx >> 6][idx & 63] = W[(size_t)(koff + k0 + (idx >> 6)) * 1024 + c0 + (idx & 63)];
    }
    __syncthreads();
    if (blockIdx.y == 0) {
        #pragma unroll
        for (int j = 0; j < 2; ++j) {
            int idx = tid + j * 256;
            int cl = idx >> 3, kc = (idx & 7) * 8;
            short8 v;
            #pragma unroll
            for (int e = 0; e < 8; ++e) v[e] = (short)f2bf(ld[kc + e][cl]);
            *(short8*)(Wxp + (size_t)(c0 + cl) * 256 + k0 + kc) = v;
        }
    } else {
        #pragma unroll
        for (int j = 0; j < 2; ++j) {
            int idx = tid + j * 256;
            int cl = idx >> 3, kc = (idx & 7) * 8;
            unsigned long long u = 0;
            #pragma unroll
            for (int e = 0; e < 8; ++e) {
                float v = ld[kc + e][cl] * WH_SCALE;
                int q = __float2int_rn(fminf(fmaxf(v, -127.f), 127.f));
                u |= (unsigned long long)(unsigned char)(signed char)q << (8 * e);
            }
            *(unsigned long long*)(Wq + (size_t)(c0 + cl) * 256 + k0 + kc) = u;
        }
    }
}

// X projection v2: block = 64 rows of one t. Stage gathered emb rows to LDS
// ONCE (bf16, stride 264), then loop 1024 cols in 4 chunks of 256.
// X element offset: t*1048576 + rblk*16384 + slot*256 + L*4  (slot = zcol/16)
__global__ __launch_bounds__(256, 2)
void xproj_kernel(const float* __restrict__ emb,
                  const int* __restrict__ idq, const int* __restrict__ idr,
                  const unsigned short* __restrict__ Wxp,
                  unsigned short* __restrict__ X)
{
    __shared__ __align__(16) unsigned short As[64 * 264];
    const int tid = threadIdx.x;
    const int mb = blockIdx.x * 64;
    const int t = mb >> 10, r0 = mb & 1023;

    // ---- stage emb -> LDS (one pass) ----
    #pragma unroll
    for (int i = 0; i < 8; ++i) {
        int task = tid + i * 256;             // 64 rows x 32 k-chunks of 8
        int rl = task >> 5, kc = (task & 31) * 8;
        int gr = r0 + rl;
        int id = (gr < 512) ? idq[gr * TTs + t] : idr[(gr - 512) * TTs + t];
        const float* ep = emb + (size_t)id * 256 + kc;
        float4 e0 = *(const float4*)ep;
        float4 e1 = *(const float4*)(ep + 4);
        short8 v;
        v[0] = (short)f2bf(e0.x); v[1] = (short)f2bf(e0.y);
        v[2] = (short)f2bf(e0.z); v[3] = (short)f2bf(e0.w);
        v[4] = (short)f2bf(e1.x); v[5] = (short)f2bf(e1.y);
        v[6] = (short)f2bf(e1.z); v[7] = (short)f2bf(e1.w);
        *(short8*)(As + rl * 264 + kc) = v;
    }
    __syncthreads();

    const int L = tid & 63, w = tid >> 6;
    const int lanelo = L & 15, lhi = L >> 4;
    const unsigned short* arow = As + (w * 16 + lanelo) * 264 + lhi * 8;
    const unsigned short* bbase = Wxp + (size_t)lanelo * 256 + lhi * 8;
    const int rblk = (r0 >> 4) + w;

    for (int cb = 0; cb < 4; ++cb) {
        f32x4 acc[16];
        #pragma unroll
        for (int f = 0; f < 16; ++f) acc[f] = (f32x4){0.f, 0.f, 0.f, 0.f};
        #pragma unroll
        for (int ks = 0; ks < 8; ++ks) {
            short8 a = *(const short8*)(arow + ks * 32);
            #pragma unroll
            for (int f = 0; f < 16; ++f) {
                short8 b = *(const short8*)(bbase + (size_t)(cb * 256 + f * 16) * 256 + ks * 32);
                acc[f] = __builtin_amdgcn_mfma_f32_16x16x32_bf16(a, b, acc[f], 0, 0, 0);
            }
        }
        #pragma unroll
        for (int f = 0; f < 16; ++f) {
            int slot = cb * 16 + f;
            size_t off = (((size_t)(t * 64 + rblk)) * 64 + slot) * 256 + L * 4;
            ushort4v v;
            v[0] = f2bf(acc[f][0]); v[1] = f2bf(acc[f][1]);
            v[2] = f2bf(acc[f][2]); v[3] = f2bf(acc[f][3]);
            *(ushort4v*)(X + off) = v;
        }
    }
}

// Recurrent loop, int8 MFMA: 64 blocks x 16 rows, 16 waves.
// Wave w owns z-cols {g*256 + w*16 + lanelo | g=0..3}; Wq slice = 64 VGPRs
// (register-resident; __launch_bounds__(1024,4) caps at 128 VGPR so it FITS).
// h int8 double-buffered in LDS (stride 272 B -> conflict-free b128 reads).
__global__ __launch_bounds__(1024, 4)
void lstm_i8_kernel(const unsigned short* __restrict__ X,
                    const signed char* __restrict__ Wq,
                    const float* __restrict__ bias,
                    const float* __restrict__ p_i, const float* __restrict__ p_f,
                    const float* __restrict__ p_o,
                    const int* __restrict__ lenq, const int* __restrict__ lenr,
                    unsigned short* __restrict__ hfin)
{
    __shared__ int hl_i[2176];                 // 2 x 16 x 272 bytes
    char* hlb = (char*)hl_i;
    const int tid = threadIdx.x;
    const int L = tid & 63, w = tid >> 6;      // w 0..15
    const int blk = blockIdx.x;
    const int r0g = blk * 16;
    const int lanelo = L & 15, lhi = L >> 4;
    const int hh = w * 16 + lanelo;

    for (int i = tid; i < 2176; i += 1024) hl_i[i] = 0;

    // ---- Wh slice (int8) -> registers, persistent ----
    int4v Bw[4][4];
    #pragma unroll
    for (int g = 0; g < 4; ++g)
        #pragma unroll
        for (int kc = 0; kc < 4; ++kc)
            Bw[g][kc] = *(const int4v*)(Wq + (size_t)(g * 256 + hh) * 256 + kc * 64 + lhi * 16);

    int xoff[4];
    #pragma unroll
    for (int g = 0; g < 4; ++g) xoff[g] = (g * 16 + w) * 256 + L * 4;
    const unsigned short* xb = X + (size_t)blk * 16384;

    const int ard = lanelo * 272 + lhi * 16;   // A-frag read base (bytes)
    const int awr = (lhi * 4) * 272 + hh;      // h write base (bytes)

    const float bi  = bias[hh];
    const float bj  = bias[256 + hh];
    const float bf_ = bias[512 + hh] + 2.0f;   // + FORGET_BIAS
    const float bo  = bias[768 + hh];
    const float pii = p_i[hh], pff = p_f[hh], poo = p_o[hh];
    const float INV = 1.f / (H_SCALE * WH_SCALE);

    int len_[4];
    #pragma unroll
    for (int reg = 0; reg < 4; ++reg) {
        int gr = r0g + lhi * 4 + reg;
        len_[reg] = (gr < 512) ? lenq[gr] : lenr[gr - 512];
    }

    float cst[4] = {};
    unsigned short hreg[4] = {};

    __syncthreads();

    for (int t = 0; t < NSTEP; ++t) {
        const int rb = (t & 1) * 4352;
        const int wb = 4352 - rb;
        const unsigned short* xt = xb + (size_t)t * 1048576;

        ushort4v xr[4];                        // consumed at gate time
        #pragma unroll
        for (int g = 0; g < 4; ++g) xr[g] = *(const ushort4v*)(xt + xoff[g]);

        int4v acc[4];
        #pragma unroll
        for (int g = 0; g < 4; ++g) acc[g] = (int4v){0, 0, 0, 0};

        #pragma unroll
        for (int kc = 0; kc < 4; ++kc) {
            int4v a = *(const int4v*)(hlb + rb + ard + kc * 64);
            #pragma unroll
            for (int g = 0; g < 4; ++g)
                acc[g] = __builtin_amdgcn_mfma_i32_16x16x64_i8(a, Bw[g][kc], acc[g], 0, 0, 0);
        }

        #pragma unroll
        for (int reg = 0; reg < 4; ++reg) {
            float cv = cst[reg];
            float zi = (float)acc[0][reg] * INV + bf2f(xr[0][reg]) + bi;
            float zj = (float)acc[1][reg] * INV + bf2f(xr[1][reg]) + bj;
            float zf = (float)acc[2][reg] * INV + bf2f(xr[2][reg]) + bf_;
            float zo = (float)acc[3][reg] * INV + bf2f(xr[3][reg]) + bo;
            float iv = sigm(zi + pii * cv);
            float fv = sigm(zf + pff * cv);
            float jv = ftanh(zj);
            float cn = fv * cv + iv * jv;
            float ov = sigm(zo + poo * cn);
            float hn = ov * ftanh(cn);
            bool upd = (t < len_[reg]);
            float hsel = upd ? hn : bf2f(hreg[reg]);
            if (upd) cst[reg] = cn;
            hreg[reg] = f2bf(hsel);
            float hq = bf2f(hreg[reg]);        // quantize the bf16-rounded value
            hlb[wb + awr + reg * 272] = (signed char)__float2int_rn(hq * H_SCALE);
        }
        __syncthreads();
    }

    #pragma unroll
    for (int reg = 0; reg < 4; ++reg)
        hfin[(size_t)(r0g + lhi * 4 + reg) * 256 + hh] = hreg[reg];
}

#define TS 64
#define KT 16
#define LDW (TS + 4)

// qM[512x256] = bf16 h(rows 0..511) @ fp32 M[256x256]
__global__ __launch_bounds__(256)
void gemm_qM_kernel(const unsigned short* __restrict__ hA, const float* __restrict__ B,
                    float* __restrict__ C)
{
    __shared__ float As[KT][LDW];
    __shared__ float Bs[KT][LDW];
    const int tid = threadIdx.x;
    const int tx = tid & 15, ty = tid >> 4;
    const int m0 = blockIdx.x * TS, n0 = blockIdx.y * TS;
    float acc[4][4] = {};
    for (int kk = 0; kk < 256; kk += KT) {
        #pragma unroll
        for (int i = 0; i < 4; ++i) {
            int l = tid + i * 256;
            As[l & 15][l >> 4] = bf2f(hA[(m0 + (l >> 4)) * 256 + kk + (l & 15)]);
            Bs[l >> 6][l & 63] = B[(kk + (l >> 6)) * 256 + n0 + (l & 63)];
        }
        __syncthreads();
        #pragma unroll
        for (int k = 0; k < KT; ++k) {
            float4 a4 = *(const float4*)&As[k][ty * 4];
            float4 b4 = *(const float4*)&Bs[k][tx * 4];
            float av[4] = {a4.x, a4.y, a4.z, a4.w};
            float bv[4] = {b4.x, b4.y, b4.z, b4.w};
            #pragma unroll
            for (int i = 0; i < 4; ++i)
                #pragma unroll
                for (int j = 0; j < 4; ++j)
                    acc[i][j] = fmaf(av[i], bv[j], acc[i][j]);
        }
        __syncthreads();
    }
    #pragma unroll
    for (int i = 0; i < 4; ++i) {
        float4 v = {acc[i][0], acc[i][1], acc[i][2], acc[i][3]};
        *(float4*)&C[(m0 + ty * 4 + i) * 256 + n0 + tx * 4] = v;
    }
}

// D[512x512] = fp32 qM[512x256] @ (bf16 r[512x256])^T
__global__ __launch_bounds__(256)
void gemm_D_kernel(const float* __restrict__ A, const unsigned short* __restrict__ hB,
                   float* __restrict__ C)
{
    __shared__ float As[KT][LDW];
    __shared__ float Bs[KT][LDW];
    const int tid = threadIdx.x;
    const int tx = tid & 15, ty = tid >> 4;
    const int m0 = blockIdx.x * TS, n0 = blockIdx.y * TS;
    float acc[4][4] = {};
    for (int kk = 0; kk < 256; kk += KT) {
        #pragma unroll
        for (int i = 0; i < 4; ++i) {
            int l = tid + i * 256;
            As[l & 15][l >> 4] = A[(m0 + (l >> 4)) * 256 + kk + (l & 15)];
            Bs[l & 15][l >> 4] = bf2f(hB[(n0 + (l >> 4)) * 256 + kk + (l & 15)]);
        }
        __syncthreads();
        #pragma unroll
        for (int k = 0; k < KT; ++k) {
            float4 a4 = *(const float4*)&As[k][ty * 4];
            float4 b4 = *(const float4*)&Bs[k][tx * 4];
            float av[4] = {a4.x, a4.y, a4.z, a4.w};
            float bv[4] = {b4.x, b4.y, b4.z, b4.w};
            #pragma unroll
            for (int i = 0; i < 4; ++i)
                #pragma unroll
                for (int j = 0; j < 4; ++j)
                    acc[i][j] = fmaf(av[i], bv[j], acc[i][j]);
        }
        __syncthreads();
    }
    #pragma unroll
    for (int i = 0; i < 4; ++i) {
        float4 v = {acc[i][0], acc[i][1], acc[i][2], acc[i][3]};
        *(float4*)&C[(m0 + ty * 4 + i) * 512 + n0 + tx * 4] = v;
    }
}

__global__ __launch_bounds__(256)
void loss_kernel(const float* __restrict__ D, const float* __restrict__ wd,
                 float* __restrict__ out)
{
    int idx = blockIdx.x * 256 + threadIdx.x;
    int j = idx & 511;
    float d   = D[idx];
    float pos = D[j * 512 + j];
    float ww  = wd[idx];
    float wp  = wd[j * 512 + j];
    float wn  = fmaxf(0.f, ww / wp - 1.f);
    float v   = fmaxf(0.f, d - pos + wn);
    #pragma unroll
    for (int o = 32; o > 0; o >>= 1) v += __shfl_down(v, o);
    __shared__ float sm[4];
    if ((threadIdx.x & 63) == 0) sm[threadIdx.x >> 6] = v;
    __syncthreads();
    if (threadIdx.x == 0) atomicAdd(out, sm[0] + sm[1] + sm[2] + sm[3]);
}

extern "C" void kernel_launch(void* const* d_in, const int* in_sizes, int n_in,
                              void* d_out, int out_size, void* d_ws, size_t ws_size,
                              hipStream_t stream) {
    const int*   idq  = (const int*)d_in[0];
    const int*   idr  = (const int*)d_in[1];
    const int*   lenq = (const int*)d_in[2];
    const int*   lenr = (const int*)d_in[3];
    const float* wd   = (const float*)d_in[4];
    const float* emb  = (const float*)d_in[5];
    const float* W    = (const float*)d_in[6];
    const float* bias = (const float*)d_in[7];
    const float* p_i  = (const float*)d_in[8];
    const float* p_f  = (const float*)d_in[9];
    const float* p_o  = (const float*)d_in[10];
    const float* Mm   = (const float*)d_in[11];
    float* out = (float*)d_out;

    char* ws = (char*)d_ws;
    unsigned short* X    = (unsigned short*)ws;           // 49*1024*1024 bf16 = 102,760,448 B
    char* p = ws + (size_t)NSTEP * 1048576 * 2;
    unsigned short* hfin = (unsigned short*)p;  p += 1024 * 256 * 2;   // 512 KB
    unsigned short* Wxp  = (unsigned short*)p;  p += 1024 * 256 * 2;   // 512 KB
    signed char*    Wq   = (signed char*)p;     p += 1024 * 256;       // 256 KB
    float* qM = (float*)p;  p += 512 * 256 * 4;                        // 512 KB
    float* D  = (float*)p;                                             // 1 MB

    init_kernel<<<1, 64, 0, stream>>>(out);
    pack_w_kernel<<<dim3(64, 2), 256, 0, stream>>>(W, Wxp, Wq);
    xproj_kernel<<<784, 256, 0, stream>>>(emb, idq, idr, Wxp, X);
    lstm_i8_kernel<<<64, 1024, 0, stream>>>(X, Wq, bias, p_i, p_f, p_o,
                                            lenq, lenr, hfin);
    gemm_qM_kernel<<<dim3(8, 4), 256, 0, stream>>>(hfin, Mm, qM);
    gemm_D_kernel<<<dim3(8, 8), 256, 0, stream>>>(qM, hfin + 512 * 256, D);
    loss_kernel<<<1024, 256, 0, stream>>>(D, wd, out);
}